// Round 3
// baseline (392.015 us; speedup 1.0000x reference)
//
#include <hip/hip_runtime.h>
#include <math.h>

// B=512, IN_CORES=12, N_PRIM=12, N_PAR=10, RFPC=4, RF=64, CAP=256
// out = concat( sigmoid MLP output (512,3072) f32 , x_sum (512,2560) f32 )
//
// R3 == R2 resubmit (R2 failed on infra: "container failed twice", no
// counters). Static audit found no OOB / barrier-divergence hazards.
//
// R2 changes vs R1 (384 us):
//  1. convT standalone kernel eliminated: transpose tiles co-scheduled as
//     guest blocks inside the capsule/MLP kernels (idle-CU hiding). Kernel
//     boundaries enforce Wt1 ready before gemm_l1, Wt2 before L2 GEMM,
//     Wt3 before L3 GEMM.
//  2. All leading dims padded +16 elems (de-pow2 strides: Wt3 8192B, h2
//     8192B, Pbuf 16KB were pow2 -> channel camping candidates).
//  3. caps_gemm2: Sk LDS buffer removed (skip written to xsum, read back
//     after barrier) -> LDS 28KB, fits fused-kernel budget.

#define BATCH 512
#define OUT0_SZ (512*3072)

#define KP1 2576     // Wt1 row stride (bf16), 5152 B
#define KP2 5136     // Wt2 row stride, 10272 B
#define KP3 4112     // Wt3 row stride, 8224 B
#define LD_XREC 2576
#define LD_H1 5136
#define LD_H2 4112
#define LDP2 4224    // Pbuf f32 stride for L2 (16896 B)
#define LDP3 3200    // Pbuf f32 stride for L3 (12800 B)
#define SPLITK 4

typedef __attribute__((ext_vector_type(8))) short short8;   // 8 x bf16
typedef __attribute__((ext_vector_type(4))) float f32x4;

__device__ inline unsigned short f2bf(float f) {
    union { float f; unsigned u; } v; v.f = f;
    unsigned r = v.u + 0x7fffu + ((v.u >> 16) & 1u);   // RNE
    return (unsigned short)(r >> 16);
}
__device__ inline float bf2f(unsigned int hi16) {
    union { unsigned u; float f; } v; v.u = hi16 << 16; return v.f;
}

#define GLD16(g, l) __builtin_amdgcn_global_load_lds( \
    (const __attribute__((address_space(1))) unsigned int*)(g), \
    (__attribute__((address_space(3))) unsigned int*)(l), 16, 0, 0)

#define GUEST_SMEM 16640   // 64*65 f32

#define CONV_PARAMS const float* __restrict__ cWr1, unsigned short* __restrict__ cWt1, \
    const float* __restrict__ cWr2, unsigned short* __restrict__ cWt2, \
    const float* __restrict__ cWr3, unsigned short* __restrict__ cWt3

// ---------------------------------------------------------------------------
// Guest: one 64x64 transpose tile (f32 [K][N] -> bf16 [N][K] padded stride).
// Tile index space: [0,3200) Wt1 | [3200,8320) Wt2 | [8320,11392) Wt3.
// ---------------------------------------------------------------------------
__device__ void conv_guest(int t, char* smem, CONV_PARAMS)
{
    float* sh = (float*)smem;
    const float* W; unsigned short* Wt;
    int Kr, Nr, Kp, ktiles, rem;
    if (t < 3200)      { W = cWr1; Wt = cWt1; Kr = 2560; Nr = 5000; Kp = KP1; ktiles = 40; rem = t; }
    else if (t < 8320) { W = cWr2; Wt = cWt2; Kr = 5000; Nr = 4000; Kp = KP2; ktiles = 80; rem = t - 3200; }
    else               { W = cWr3; Wt = cWt3; Kr = 4000; Nr = 3072; Kp = KP3; ktiles = 64; rem = t - 8320; }
    int k0 = (rem % ktiles) * 64;
    int n0 = (rem / ktiles) * 64;
    int tid = threadIdx.x;

    {
        int kr = tid >> 4;
        int nc = (tid & 15) * 4;
        #pragma unroll
        for (int p = 0; p < 4; ++p) {
            int k = k0 + kr + p * 16;
            float4 v = make_float4(0.f, 0.f, 0.f, 0.f);
            if (k < Kr) {
                if (n0 + nc + 3 < Nr) {
                    v = *(const float4*)&W[(size_t)k * Nr + n0 + nc];
                } else {
                    float tmp[4] = {0.f, 0.f, 0.f, 0.f};
                    #pragma unroll
                    for (int j = 0; j < 4; ++j)
                        if (n0 + nc + j < Nr) tmp[j] = W[(size_t)k * Nr + n0 + nc + j];
                    v = make_float4(tmp[0], tmp[1], tmp[2], tmp[3]);
                }
            }
            float* row = &sh[(kr + p * 16) * 65 + nc];
            row[0] = v.x; row[1] = v.y; row[2] = v.z; row[3] = v.w;
        }
    }
    __syncthreads();
    {
        int nr = tid >> 2;
        int kc = (tid & 3) * 16;
        unsigned int u[8];
        #pragma unroll
        for (int j = 0; j < 8; ++j) {
            float v0 = sh[(kc + 2 * j)     * 65 + nr];
            float v1 = sh[(kc + 2 * j + 1) * 65 + nr];
            u[j] = (unsigned int)f2bf(v0) | ((unsigned int)f2bf(v1) << 16);
        }
        unsigned int* dst = (unsigned int*)&Wt[(size_t)(n0 + nr) * Kp + k0 + kc];
        *(uint4*)(dst)     = make_uint4(u[0], u[1], u[2], u[3]);
        *(uint4*)(dst + 4) = make_uint4(u[4], u[5], u[6], u[7]);
    }
}

// ---------------------------------------------------------------------------
// Small standalone: capsule weight transposes W1 (48) + W2 (40), 64x64 each.
// Must precede caps_gemm1 (reads W1t).
// ---------------------------------------------------------------------------
__global__ __launch_bounds__(256) void conv_small(
    const float* __restrict__ W1, unsigned short* __restrict__ W1t,
    const float* __restrict__ W2, unsigned short* __restrict__ W2t)
{
    __shared__ __align__(16) float sh[64 * 65];
    int bid = blockIdx.x;
    const float* W; unsigned short* Wt;
    if (bid < 48) { W = W1 + (size_t)bid * 4096; Wt = W1t + (size_t)bid * 4096; }
    else          { W = W2 + (size_t)(bid - 48) * 4096; Wt = W2t + (size_t)(bid - 48) * 4096; }
    int tid = threadIdx.x;
    int kr = tid >> 4, nc = (tid & 15) * 4;
    #pragma unroll
    for (int p = 0; p < 4; ++p) {
        float4 v = *(const float4*)&W[(size_t)(kr + p * 16) * 64 + nc];
        float* row = &sh[(kr + p * 16) * 65 + nc];
        row[0] = v.x; row[1] = v.y; row[2] = v.z; row[3] = v.w;
    }
    __syncthreads();
    int nr = tid >> 2, kc = (tid & 3) * 16;
    unsigned int u[8];
    #pragma unroll
    for (int j = 0; j < 8; ++j) {
        float v0 = sh[(kc + 2 * j)     * 65 + nr];
        float v1 = sh[(kc + 2 * j + 1) * 65 + nr];
        u[j] = (unsigned int)f2bf(v0) | ((unsigned int)f2bf(v1) << 16);
    }
    unsigned int* dst = (unsigned int*)&Wt[(size_t)nr * 64 + kc];
    *(uint4*)(dst)     = make_uint4(u[0], u[1], u[2], u[3]);
    *(uint4*)(dst + 4) = make_uint4(u[4], u[5], u[6], u[7]);
}

// ---------------------------------------------------------------------------
// Capsule layer 1 (host 192 blocks) + conv guests.
// ---------------------------------------------------------------------------
__global__ __launch_bounds__(256) void caps_gemm1_f(
    const float* __restrict__ x, const float* __restrict__ C1,
    const unsigned short* __restrict__ W1t, const float* __restrict__ b1,
    unsigned short* __restrict__ xp, int hostBlocks, int guestBase,
    CONV_PARAMS)
{
    __shared__ __align__(16) char smem[27840];
    if ((int)blockIdx.x >= hostBlocks) {
        conv_guest(guestBase + blockIdx.x - hostBlocks, smem, cWr1, cWt1, cWr2, cWt2, cWr3, cWt3);
        return;
    }
    unsigned short* As = (unsigned short*)smem;            // 128*72
    unsigned short* Bs = (unsigned short*)(smem + 18432);  // 64*72
    float* Csh = (float*)(smem + 27648);                   // 48

    int kl = blockIdx.x % 48;
    int bm = (blockIdx.x / 48) * 128;
    int tid = threadIdx.x;
    int w = tid >> 6, lane = tid & 63, q = lane >> 4, r16 = lane & 15;
    int wm = (w >> 1) * 64, wn = (w & 1) * 32;

    if (tid < 48) Csh[tid] = C1[tid * 48 + kl];
    {
        const uint4* src = (const uint4*)(W1t + (size_t)kl * 4096);
        #pragma unroll
        for (int p = 0; p < 2; ++p) {
            int c = tid + p * 256;
            int row = c >> 3, cq = c & 7;
            *(uint4*)&Bs[row * 72 + cq * 8] = src[c];
        }
    }
    __syncthreads();

    int arow = tid >> 1, ah = (tid & 1) * 32;
    float accp[32];
    #pragma unroll
    for (int i = 0; i < 32; ++i) accp[i] = 0.f;
    const float* xrow = x + (size_t)(bm + arow) * 3072 + ah;
    for (int ij = 0; ij < 48; ++ij) {
        float c = Csh[ij];
        if (c != 0.f) {
            const float4* p4 = (const float4*)(xrow + ij * 64);
            #pragma unroll
            for (int cc = 0; cc < 8; ++cc) {
                float4 v = p4[cc];
                accp[cc * 4 + 0] = fmaf(c, v.x, accp[cc * 4 + 0]);
                accp[cc * 4 + 1] = fmaf(c, v.y, accp[cc * 4 + 1]);
                accp[cc * 4 + 2] = fmaf(c, v.z, accp[cc * 4 + 2]);
                accp[cc * 4 + 3] = fmaf(c, v.w, accp[cc * 4 + 3]);
            }
        }
    }
    {
        unsigned short* dst = &As[arow * 72 + ah];
        #pragma unroll
        for (int cc = 0; cc < 4; ++cc) {
            unsigned int u[4];
            #pragma unroll
            for (int j = 0; j < 4; ++j)
                u[j] = (unsigned int)f2bf(accp[cc * 8 + 2 * j]) |
                       ((unsigned int)f2bf(accp[cc * 8 + 2 * j + 1]) << 16);
            *(uint4*)&dst[cc * 8] = make_uint4(u[0], u[1], u[2], u[3]);
        }
    }
    __syncthreads();

    f32x4 acc[4][2];
    #pragma unroll
    for (int i = 0; i < 4; ++i)
        #pragma unroll
        for (int j = 0; j < 2; ++j) acc[i][j] = (f32x4)0.f;
    #pragma unroll
    for (int ks = 0; ks < 2; ++ks) {
        short8 a[4], b[2];
        #pragma unroll
        for (int mt = 0; mt < 4; ++mt)
            a[mt] = *(const short8*)&As[(wm + mt * 16 + r16) * 72 + ks * 32 + q * 8];
        #pragma unroll
        for (int nt = 0; nt < 2; ++nt)
            b[nt] = *(const short8*)&Bs[(wn + nt * 16 + r16) * 72 + ks * 32 + q * 8];
        #pragma unroll
        for (int mt = 0; mt < 4; ++mt)
            #pragma unroll
            for (int nt = 0; nt < 2; ++nt)
                acc[mt][nt] = __builtin_amdgcn_mfma_f32_16x16x32_bf16(a[mt], b[nt], acc[mt][nt], 0, 0, 0);
    }

    #pragma unroll
    for (int mt = 0; mt < 4; ++mt) {
        #pragma unroll
        for (int nt = 0; nt < 2; ++nt) {
            int n = wn + nt * 16 + r16;
            float bv = b1[kl * 64 + n];
            #pragma unroll
            for (int reg = 0; reg < 4; ++reg) {
                int row = bm + wm + mt * 16 + q * 4 + reg;
                xp[(size_t)row * 3072 + kl * 64 + n] = f2bf(fmaxf(acc[mt][nt][reg] + bv, 0.f));
            }
        }
    }
}

// ---------------------------------------------------------------------------
// Capsule layer 2 + skip + norms (host 160 blocks) + conv guests.
// Skip written directly to xsum, read back after barrier (no Sk LDS).
// ---------------------------------------------------------------------------
__global__ __launch_bounds__(256) void caps_gemm2_f(
    const unsigned short* __restrict__ xp, const float* __restrict__ Cs,
    const float* __restrict__ C2, const unsigned short* __restrict__ W2t,
    const float* __restrict__ b2, float* __restrict__ xsum,
    float* __restrict__ part8, int hostBlocks, int guestBase,
    CONV_PARAMS)
{
    __shared__ __align__(16) char smem[28032];
    if ((int)blockIdx.x >= hostBlocks) {
        conv_guest(guestBase + blockIdx.x - hostBlocks, smem, cWr1, cWt1, cWr2, cWt2, cWr3, cWt3);
        return;
    }
    unsigned short* As = (unsigned short*)smem;
    unsigned short* Bs = (unsigned short*)(smem + 18432);
    float* C2sh = (float*)(smem + 27648);
    float* Cssh = (float*)(smem + 27840);

    int kl = blockIdx.x % 40;
    int bm = (blockIdx.x / 40) * 128;
    int tid = threadIdx.x;
    int w = tid >> 6, lane = tid & 63, q = lane >> 4, r16 = lane & 15;
    int wm = (w >> 1) * 64, wn = (w & 1) * 32;
    int half = w & 1;

    if (tid < 48) { C2sh[tid] = C2[tid * 40 + kl]; Cssh[tid] = Cs[tid * 40 + kl]; }
    {
        const uint4* src = (const uint4*)(W2t + (size_t)kl * 4096);
        #pragma unroll
        for (int p = 0; p < 2; ++p) {
            int c = tid + p * 256;
            int row = c >> 3, cq = c & 7;
            *(uint4*)&Bs[row * 72 + cq * 8] = src[c];
        }
    }
    __syncthreads();

    int arow = tid >> 1, ah = (tid & 1) * 32;
    float accp[32], skp[32];
    #pragma unroll
    for (int i = 0; i < 32; ++i) { accp[i] = 0.f; skp[i] = 0.f; }
    const unsigned short* xprow = xp + (size_t)(bm + arow) * 3072 + ah;
    for (int ij = 0; ij < 48; ++ij) {
        float c2 = C2sh[ij], cs = Cssh[ij];
        if (c2 != 0.f || cs != 0.f) {
            const uint4* p4 = (const uint4*)(xprow + ij * 64);
            #pragma unroll
            for (int cc = 0; cc < 4; ++cc) {
                uint4 v = p4[cc];
                unsigned int uu[4] = {v.x, v.y, v.z, v.w};
                #pragma unroll
                for (int j = 0; j < 4; ++j) {
                    float lo = bf2f(uu[j] & 0xffffu);
                    float hi = bf2f(uu[j] >> 16);
                    int idx = cc * 8 + 2 * j;
                    accp[idx]     = fmaf(c2, lo, accp[idx]);
                    accp[idx + 1] = fmaf(c2, hi, accp[idx + 1]);
                    skp[idx]      = fmaf(cs, lo, skp[idx]);
                    skp[idx + 1]  = fmaf(cs, hi, skp[idx + 1]);
                }
            }
        }
    }
    {
        unsigned short* dst = &As[arow * 72 + ah];
        #pragma unroll
        for (int cc = 0; cc < 4; ++cc) {
            unsigned int u[4];
            #pragma unroll
            for (int j = 0; j < 4; ++j)
                u[j] = (unsigned int)f2bf(accp[cc * 8 + 2 * j]) |
                       ((unsigned int)f2bf(accp[cc * 8 + 2 * j + 1]) << 16);
            *(uint4*)&dst[cc * 8] = make_uint4(u[0], u[1], u[2], u[3]);
        }
        // skip -> global xsum (read back by epilogue after barrier)
        float* sx = xsum + (size_t)(bm + arow) * 2560 + kl * 64 + ah;
        #pragma unroll
        for (int cc = 0; cc < 8; ++cc)
            *(float4*)&sx[cc * 4] = make_float4(skp[cc*4], skp[cc*4+1], skp[cc*4+2], skp[cc*4+3]);
    }
    __syncthreads();

    f32x4 acc[4][2];
    #pragma unroll
    for (int i = 0; i < 4; ++i)
        #pragma unroll
        for (int j = 0; j < 2; ++j) acc[i][j] = (f32x4)0.f;
    #pragma unroll
    for (int ks = 0; ks < 2; ++ks) {
        short8 a[4], b[2];
        #pragma unroll
        for (int mt = 0; mt < 4; ++mt)
            a[mt] = *(const short8*)&As[(wm + mt * 16 + r16) * 72 + ks * 32 + q * 8];
        #pragma unroll
        for (int nt = 0; nt < 2; ++nt)
            b[nt] = *(const short8*)&Bs[(wn + nt * 16 + r16) * 72 + ks * 32 + q * 8];
        #pragma unroll
        for (int mt = 0; mt < 4; ++mt)
            #pragma unroll
            for (int nt = 0; nt < 2; ++nt)
                acc[mt][nt] = __builtin_amdgcn_mfma_f32_16x16x32_bf16(a[mt], b[nt], acc[mt][nt], 0, 0, 0);
    }

    #pragma unroll
    for (int mt = 0; mt < 4; ++mt) {
        float sreg[4] = {0.f, 0.f, 0.f, 0.f};
        #pragma unroll
        for (int nt = 0; nt < 2; ++nt) {
            int n = wn + nt * 16 + r16;
            float bv = b2[kl * 64 + n];
            #pragma unroll
            for (int reg = 0; reg < 4; ++reg) {
                int lr = wm + mt * 16 + q * 4 + reg;
                size_t xi = (size_t)(bm + lr) * 2560 + kl * 64 + n;
                float v = xsum[xi] + fmaxf(acc[mt][nt][reg] + bv, 0.f);
                xsum[xi] = v;
                sreg[reg] += v * v;
            }
        }
        #pragma unroll
        for (int reg = 0; reg < 4; ++reg) {
            float s = sreg[reg];
            s += __shfl_xor(s, 1); s += __shfl_xor(s, 2);
            s += __shfl_xor(s, 4); s += __shfl_xor(s, 8);
            if (r16 == 0) {
                int row = bm + wm + mt * 16 + q * 4 + reg;
                part8[(size_t)row * 80 + kl * 2 + half] = s;
            }
        }
    }
}

// ---------------------------------------------------------------------------
// Norm-argmax (host 512 blocks) + conv guests. Writes only active slice.
// ---------------------------------------------------------------------------
__global__ __launch_bounds__(256) void mask_f(
    const float* __restrict__ xs, const float* __restrict__ part8,
    unsigned short* __restrict__ xrec, int* __restrict__ active,
    int hostBlocks, int guestBase, CONV_PARAMS)
{
    __shared__ __align__(16) char smem[GUEST_SMEM + 64];
    if ((int)blockIdx.x >= hostBlocks) {
        conv_guest(guestBase + blockIdx.x - hostBlocks, smem, cWr1, cWt1, cWr2, cWt2, cWr3, cWt3);
        return;
    }
    float* norms = (float*)smem;
    int* actp = (int*)(smem + 40);
    int b = blockIdx.x;
    int tid = threadIdx.x;
    if (tid < 10) {
        float s = 0.f;
        #pragma unroll
        for (int j = 0; j < 8; ++j) s += part8[(size_t)b * 80 + tid * 8 + j];
        norms[tid] = s;
    }
    __syncthreads();
    if (tid == 0) {
        int best = 0; float bn = -1.f;
        #pragma unroll
        for (int k = 0; k < 10; ++k)
            if (norms[k] > bn) { bn = norms[k]; best = k; }
        *actp = best;
        active[b] = best;
    }
    __syncthreads();
    int act = *actp;
    int idx = act * 256 + tid;
    xrec[(size_t)b * LD_XREC + idx] = f2bf(xs[(size_t)b * 2560 + idx]);
}

// ---------------------------------------------------------------------------
// Bucket rows by active capsule (host 1 block, 256 thr x 2 rows) + guests.
// ---------------------------------------------------------------------------
__global__ __launch_bounds__(256) void bucket_f(
    const int* __restrict__ active, int* __restrict__ perm,
    int4* __restrict__ slots, int hostBlocks, int guestBase, CONV_PARAMS)
{
    __shared__ __align__(16) char smem[GUEST_SMEM + 128];
    if ((int)blockIdx.x >= hostBlocks) {
        conv_guest(guestBase + blockIdx.x - hostBlocks, smem, cWr1, cWt1, cWr2, cWt2, cWr3, cWt3);
        return;
    }
    int* cnt = (int*)smem;
    int* pos = cnt + 10;
    int tid = threadIdx.x;
    if (tid < 10) cnt[tid] = 0;
    __syncthreads();
    int a0 = active[tid], a1 = active[tid + 256];
    atomicAdd(&cnt[a0], 1);
    atomicAdd(&cnt[a1], 1);
    __syncthreads();
    if (tid == 0) {
        int o = 0, s = 0;
        for (int g = 0; g < 10; ++g) {
            pos[g] = o;
            int mg = cnt[g];
            for (int t0 = 0; t0 < mg; t0 += 64)
                slots[s++] = make_int4(g, o + t0, min(64, mg - t0), 0);
            o += mg;
        }
        for (; s < 18; ++s) slots[s] = make_int4(0, 0, 0, 0);
    }
    __syncthreads();
    int r0 = atomicAdd(&pos[a0], 1);
    perm[r0] = tid;
    int r1 = atomicAdd(&pos[a1], 1);
    perm[r1] = tid + 256;
}

// ---------------------------------------------------------------------------
// Grouped MLP layer-1 GEMM (host 40x18=720 blocks) + conv guests.
// ---------------------------------------------------------------------------
__global__ __launch_bounds__(256) void gemm_l1_f(
    const unsigned short* __restrict__ xrec, const int* __restrict__ perm,
    const int4* __restrict__ slots, const unsigned short* __restrict__ Wt1,
    const float* __restrict__ br1, unsigned short* __restrict__ h1,
    int hostBlocks, int guestBase, CONV_PARAMS)
{
    __shared__ __align__(16) char smem[GUEST_SMEM];
    if ((int)blockIdx.x >= hostBlocks) {
        conv_guest(guestBase + blockIdx.x - hostBlocks, smem, cWr1, cWt1, cWr2, cWt2, cWr3, cWt3);
        return;
    }
    unsigned short* As = (unsigned short*)smem;          // 64*32
    unsigned short* Bs = (unsigned short*)(smem + 4096); // 128*32
    int* rows = (int*)(smem + 12288);                    // 64

    int sy = blockIdx.x % 18;
    int bn = (blockIdx.x / 18) * 128;
    int4 s = slots[sy];
    if (s.z == 0) return;
    int g = s.x, mstart = s.y, mval = s.z;
    int tid = threadIdx.x;

    if (tid < 64) rows[tid] = perm[mstart + min(tid, mval - 1)];
    __syncthreads();

    int w = tid >> 6, lane = tid & 63;
    int wm = (w >> 1) * 32, wn = (w & 1) * 64;
    int q = lane >> 4, r16 = lane & 15;
    int srow = tid >> 2, skq = tid & 3;

    f32x4 acc[2][4];
    #pragma unroll
    for (int i = 0; i < 2; ++i)
        #pragma unroll
        for (int j = 0; j < 4; ++j) acc[i][j] = (f32x4)0.f;

    int arow = rows[srow];
    const unsigned short* ga = xrec + (size_t)arow * LD_XREC + g * 256 + skq * 8;
    const unsigned short* gb = Wt1 + (size_t)(bn + srow) * KP1 + g * 256 + skq * 8;

    for (int kk = 0; kk < 256; kk += 32) {
        GLD16(ga + kk, &As[tid * 8]);
        GLD16(gb + kk, &Bs[tid * 8]);
        GLD16(gb + kk + (size_t)64 * KP1, &Bs[(tid + 256) * 8]);
        __syncthreads();

        short8 a[2], b[4];
        #pragma unroll
        for (int mt = 0; mt < 2; ++mt)
            a[mt] = *(const short8*)&As[(wm + mt * 16 + r16) * 32 + q * 8];
        #pragma unroll
        for (int nt = 0; nt < 4; ++nt)
            b[nt] = *(const short8*)&Bs[(wn + nt * 16 + r16) * 32 + q * 8];
        #pragma unroll
        for (int mt = 0; mt < 2; ++mt)
            #pragma unroll
            for (int nt = 0; nt < 4; ++nt)
                acc[mt][nt] = __builtin_amdgcn_mfma_f32_16x16x32_bf16(a[mt], b[nt], acc[mt][nt], 0, 0, 0);
        __syncthreads();
    }

    #pragma unroll
    for (int mt = 0; mt < 2; ++mt) {
        #pragma unroll
        for (int nt = 0; nt < 4; ++nt) {
            int n = bn + wn + nt * 16 + r16;
            float bv = (n < 5000) ? br1[n] : 0.f;
            #pragma unroll
            for (int reg = 0; reg < 4; ++reg) {
                int lm = wm + mt * 16 + q * 4 + reg;
                if (lm < mval)
                    h1[(size_t)(mstart + lm) * LD_H1 + n] =
                        f2bf(fmaxf(acc[mt][nt][reg] + bv, 0.f));
            }
        }
    }
}

// ---------------------------------------------------------------------------
// Split-K MFMA GEMM (64x128 tile, BK=32) + optional conv guests.
// Host decompose: bid -> (x = bid%nbx, y = (bid/nbx)%8, z = bid/(nbx*8)).
// ---------------------------------------------------------------------------
__global__ __launch_bounds__(256) void gemm_splitk_f(
    const unsigned short* __restrict__ A, int ldA,
    const unsigned short* __restrict__ Bt, int ldB,
    float* __restrict__ P, int ldP, int Np, int kper, int nbx,
    int hostBlocks, int guestBase, CONV_PARAMS)
{
    __shared__ __align__(16) char smem[GUEST_SMEM];
    if ((int)blockIdx.x >= hostBlocks) {
        conv_guest(guestBase + blockIdx.x - hostBlocks, smem, cWr1, cWt1, cWr2, cWt2, cWr3, cWt3);
        return;
    }
    unsigned short* As = (unsigned short*)smem;           // 64*32
    unsigned short* Bs = (unsigned short*)(smem + 4096);  // 128*32

    int tid = threadIdx.x;
    int bid = blockIdx.x;
    int bn = (bid % nbx) * 128;
    int bm = ((bid / nbx) & 7) * 64;
    int z  = bid / (nbx * 8);
    int kz = z * kper;

    int w = tid >> 6, lane = tid & 63;
    int wm = (w >> 1) * 32, wn = (w & 1) * 64;
    int q = lane >> 4, r16 = lane & 15;
    int srow = tid >> 2, skq = tid & 3;

    f32x4 acc[2][4];
    #pragma unroll
    for (int i = 0; i < 2; ++i)
        #pragma unroll
        for (int j = 0; j < 4; ++j) acc[i][j] = (f32x4)0.f;

    for (int kk = 0; kk < kper; kk += 32) {
        int k0 = kz + kk;
        const unsigned short* ga = A + (size_t)(bm + srow) * ldA + k0 + skq * 8;
        GLD16(ga, &As[tid * 8]);
        const unsigned short* gb = Bt + (size_t)(bn + srow) * ldB + k0 + skq * 8;
        GLD16(gb, &Bs[tid * 8]);
        GLD16(gb + (size_t)64 * ldB, &Bs[(tid + 256) * 8]);
        __syncthreads();

        short8 a[2], b[4];
        #pragma unroll
        for (int mt = 0; mt < 2; ++mt)
            a[mt] = *(const short8*)&As[(wm + mt * 16 + r16) * 32 + q * 8];
        #pragma unroll
        for (int nt = 0; nt < 4; ++nt)
            b[nt] = *(const short8*)&Bs[(wn + nt * 16 + r16) * 32 + q * 8];
        #pragma unroll
        for (int mt = 0; mt < 2; ++mt)
            #pragma unroll
            for (int nt = 0; nt < 4; ++nt)
                acc[mt][nt] = __builtin_amdgcn_mfma_f32_16x16x32_bf16(a[mt], b[nt], acc[mt][nt], 0, 0, 0);
        __syncthreads();
    }

    float* Pz = P + (size_t)z * 512 * ldP;
    #pragma unroll
    for (int mt = 0; mt < 2; ++mt) {
        #pragma unroll
        for (int nt = 0; nt < 4; ++nt) {
            int cn = bn + wn + nt * 16 + r16;
            #pragma unroll
            for (int reg = 0; reg < 4; ++reg) {
                int cm = bm + wm + mt * 16 + q * 4 + reg;
                Pz[(size_t)cm * ldP + cn] = acc[mt][nt][reg];
            }
        }
    }
}

// ---------------------------------------------------------------------------
// Combine split-K + bias + act (+ optional conv guests).
// MODE 0: relu->bf16 (stride ldO). MODE 1: sigmoid->f32, un-permute rows.
// ---------------------------------------------------------------------------
template<int MODE>
__global__ __launch_bounds__(256) void combine_f(
    const float* __restrict__ P, int ldP, const float* __restrict__ bias,
    void* __restrict__ out, int ldO, int Np, int N_real,
    const int* __restrict__ perm, int hostBlocks, int guestBase, CONV_PARAMS)
{
    __shared__ __align__(16) char smem[GUEST_SMEM];
    if ((int)blockIdx.x >= hostBlocks) {
        conv_guest(guestBase + blockIdx.x - hostBlocks, smem, cWr1, cWt1, cWr2, cWt2, cWr3, cWt3);
        return;
    }
    int gid = blockIdx.x * 256 + threadIdx.x;
    int n0 = (gid * 4) % Np;
    int m  = (gid * 4) / Np;
    size_t MN = (size_t)512 * ldP;
    const float* p = P + (size_t)m * ldP + n0;
    f32x4 s = *(const f32x4*)p;
    s += *(const f32x4*)(p + MN);
    s += *(const f32x4*)(p + 2 * MN);
    s += *(const f32x4*)(p + 3 * MN);
    f32x4 bv = (n0 < N_real) ? *(const f32x4*)(bias + n0) : (f32x4)0.f;
    s += bv;
    if (MODE == 0) {
        unsigned int lo = (unsigned int)f2bf(fmaxf(s[0], 0.f)) | ((unsigned int)f2bf(fmaxf(s[1], 0.f)) << 16);
        unsigned int hi = (unsigned int)f2bf(fmaxf(s[2], 0.f)) | ((unsigned int)f2bf(fmaxf(s[3], 0.f)) << 16);
        *(uint2*)((unsigned short*)out + (size_t)m * ldO + n0) = make_uint2(lo, hi);
    } else {
        int row = perm[m];
        f32x4 v;
        v[0] = 1.f / (1.f + expf(-s[0]));
        v[1] = 1.f / (1.f + expf(-s[1]));
        v[2] = 1.f / (1.f + expf(-s[2]));
        v[3] = 1.f / (1.f + expf(-s[3]));
        *(f32x4*)((float*)out + (size_t)row * ldO + n0) = v;
    }
}

extern "C" void kernel_launch(void* const* d_in, const int* in_sizes, int n_in,
                              void* d_out, int out_size, void* d_ws, size_t ws_size,
                              hipStream_t stream) {
    const float* x   = (const float*)d_in[0];
    const float* C1  = (const float*)d_in[1];
    const float* W1  = (const float*)d_in[2];
    const float* b1  = (const float*)d_in[3];
    const float* Cs  = (const float*)d_in[4];
    const float* C2  = (const float*)d_in[5];
    const float* W2  = (const float*)d_in[6];
    const float* b2  = (const float*)d_in[7];
    const float* Wr1 = (const float*)d_in[8];
    const float* br1 = (const float*)d_in[9];
    const float* Wr2 = (const float*)d_in[10];
    const float* br2 = (const float*)d_in[11];
    const float* Wr3 = (const float*)d_in[12];
    const float* br3 = (const float*)d_in[13];

    float* out = (float*)d_out;
    float* out0     = out;              // (512,3072) f32 sigmoid output
    float* xsum_out = out + OUT0_SZ;    // (512,2560) f32 x_sum

    // workspace layout (bytes)
    char* base = (char*)d_ws;
    unsigned short* xrec = (unsigned short*)(base);               // 512*2576*2  = 2,637,824
    unsigned short* h1   = (unsigned short*)(base +   2637824);   // 512*5136*2  = 5,259,264
    unsigned short* h2   = (unsigned short*)(base +   7897088);   // 512*4112*2  = 4,210,688
    unsigned short* Wt1  = (unsigned short*)(base +  12107776);   // 5120*2576*2 = 26,378,240
    unsigned short* Wt2  = (unsigned short*)(base +  38486016);   // 4096*5136*2 = 42,074,112
    unsigned short* Wt3  = (unsigned short*)(base +  80560128);   // 3072*4112*2 = 25,264,128
    float*          Pbuf = (float*)(base + 105824256);            // 4*512*4224*4= 34,603,008
    unsigned short* xp   = (unsigned short*)(base + 140427264);   // 512*3072*2  = 3,145,728
    unsigned short* W1t  = (unsigned short*)(base + 143572992);   //     393,216
    unsigned short* W2t  = (unsigned short*)(base + 143966208);   //     327,680
    float*          part8= (float*)(base + 144293888);            //     163,840
    int*  active = (int*)(base + 144457728);                      //       2,048
    int*  perm   = active + 512;                                  //       2,048
    int4* slots  = (int4*)(perm + 512);                           //         288
    // total ~144.5 MB

    #define CARGS Wr1, Wt1, Wr2, Wt2, Wr3, Wt3

    // capsule weight transposes (needed by caps path)
    conv_small<<<88, 256, 0, stream>>>(W1, W1t, W2, W2t);

    // capsule path + co-scheduled MLP-weight transpose guests.
    // T1 (Wt1, 3200 tiles): caps1 1600 + caps2 1600  -> done before gemm_l1
    // T2 (Wt2, 5120): mask 1300 + bucket 1300 + gemm_l1 2520 -> before L2 gemm
    // T3 (Wt3, 3072): L2 gemm 2000 + combine-L2 1072 -> before L3 gemm
    caps_gemm1_f<<<192 + 1600, 256, 0, stream>>>(x, C1, W1t, b1, xp, 192, 0, CARGS);
    caps_gemm2_f<<<160 + 1600, 256, 0, stream>>>(xp, Cs, C2, W2t, b2, xsum_out, part8, 160, 1600, CARGS);
    mask_f<<<512 + 1300, 256, 0, stream>>>(xsum_out, part8, xrec, active, 512, 3200, CARGS);
    bucket_f<<<1 + 1300, 256, 0, stream>>>(active, perm, slots, 1, 4500, CARGS);

    // MLP layer 1 (grouped, K=256) -> h1 (permuted rows)
    gemm_l1_f<<<720 + 2520, 256, 0, stream>>>(xrec, perm, slots, Wt1, br1, h1, 720, 5800, CARGS);

    // MLP layer 2: (512,5120) @ Wt2^T -> h2
    gemm_splitk_f<<<1024 + 2000, 256, 0, stream>>>(h1, LD_H1, Wt2, KP2, Pbuf, LDP2, 4096, 5120 / SPLITK, 32, 1024, 8320, CARGS);
    combine_f<0><<<2048 + 1072, 256, 0, stream>>>(Pbuf, LDP2, br2, h2, LD_H2, 4096, 4000, nullptr, 2048, 10320, CARGS);

    // MLP layer 3: (512,4096) @ Wt3^T -> out0 (un-permuted)
    gemm_splitk_f<<<768, 256, 0, stream>>>(h2, LD_H2, Wt3, KP3, Pbuf, LDP3, 3072, 4096 / SPLITK, 24, 768, 0, CARGS);
    combine_f<1><<<1536, 256, 0, stream>>>(Pbuf, LDP3, br3, out0, 3072, 3072, 3072, perm, 1536, 0, CARGS);
}